// Round 1
// baseline (119.907 us; speedup 1.0000x reference)
//
#include <hip/hip_runtime.h>
#include <cstdint>
#include <math.h>

// Problem constants (fixed by the reference: trimap [4,320,320,1]).
constexpr int B = 4;
constexpr int H = 320;
constexpr int W = 320;

// ---------------------------------------------------------------------------
// Kernel 1: exact 1-D row EDT for both values (0 and 255) simultaneously.
// One block per (b,h) row, 320 threads. Masks staged in LDS as bit-pairs;
// inner loop reads are same-address broadcasts (conflict-free).
// Distances are small ints (<=319) or sentinel 1000; packed as u16|u16<<16.
// ---------------------------------------------------------------------------
__global__ __launch_bounds__(W) void row_edt_kernel(const int* __restrict__ tri,
                                                    uint32_t* __restrict__ packed) {
    __shared__ uint32_t mask[W];
    const int row = blockIdx.x;                 // b*H + h
    const int w   = threadIdx.x;
    const int v   = tri[row * W + w];
    mask[w] = (v == 0 ? 1u : 0u) | (v == 255 ? 2u : 0u);
    __syncthreads();

    int d0 = 1000, d1 = 1000;                   // sentinel: value absent in row
    #pragma unroll 8
    for (int j = 0; j < W; ++j) {
        const uint32_t m = mask[j];
        const int dist = (w > j) ? (w - j) : (j - w);
        if (m & 1u) d0 = min(d0, dist);
        if (m & 2u) d1 = min(d1, dist);
    }
    packed[row * W + w] = (uint32_t)d0 | ((uint32_t)d1 << 16);
}

// ---------------------------------------------------------------------------
// Kernel 2: column pass  D2[i,w] = min_k d1[k,w]^2 + (i-k)^2  (exact, int),
// fused with the Gaussian/quantize epilogue for all 6 output channels.
// Block: 32 w-cols x 32 i-rows tile, 256 threads (8 i-groups x 32 w),
// 4 i-values per thread. Full 320-row packed column tile staged in LDS (40KB).
// ---------------------------------------------------------------------------
constexpr int WTILE = 32;
constexpr int ITILE = 32;
constexpr int NR    = 4;   // i-values per thread = ITILE / 8 groups

__global__ __launch_bounds__(256) void col_edt_kernel(const uint32_t* __restrict__ packed,
                                                      float* __restrict__ out) {
    __shared__ uint32_t pk[H * WTILE];          // 40 KB
    const int w0  = blockIdx.x * WTILE;
    const int i0  = blockIdx.y * ITILE;
    const int b   = blockIdx.z;
    const int tid = threadIdx.x;

    const uint32_t* base = packed + b * H * W;
    for (int idx = tid; idx < H * WTILE; idx += 256) {
        pk[idx] = base[(idx >> 5) * W + w0 + (idx & 31)];
    }
    __syncthreads();

    const int tx = tid & 31;    // w within tile
    const int tg = tid >> 5;    // i-group 0..7

    int m0[NR], m1[NR], dy[NR];
    #pragma unroll
    for (int r = 0; r < NR; ++r) {
        m0[r] = 0x7fffffff;
        m1[r] = 0x7fffffff;
        dy[r] = i0 + tg + 8 * r;                // i - k, starts at k=0
    }

    for (int k = 0; k < H; ++k) {
        const uint32_t m = pk[k * WTILE + tx];  // broadcast pairs, conflict-free
        const int a  = (int)(m & 0xffffu);
        const int c  = (int)(m >> 16);
        const int g0 = a * a;
        const int g1 = c * c;
        #pragma unroll
        for (int r = 0; r < NR; ++r) {
            const int dd = dy[r] * dy[r];
            m0[r] = min(m0[r], g0 + dd);
            m1[r] = min(m1[r], g1 + dd);
            dy[r] -= 1;
        }
    }

    // Epilogue: 2*sigma^2 for sigma = 6.4, 25.6, 51.2 (f32 constants exactly
    // as the reference forms them). True division + rintf (half-to-even)
    // mirrors jnp's  clip(round(exp(-d2/(2 s^2)) * 255), 0, 255).
    const float cc0 = 81.92f, cc1 = 1310.72f, cc2 = 5242.88f;
    #pragma unroll
    for (int r = 0; r < NR; ++r) {
        const int i = i0 + tg + 8 * r;
        const float da = (float)m0[r];
        const float db = (float)m1[r];
        float q0 = fminf(fmaxf(rintf(expf(-da / cc0) * 255.0f), 0.0f), 255.0f);
        float q1 = fminf(fmaxf(rintf(expf(-da / cc1) * 255.0f), 0.0f), 255.0f);
        float q2 = fminf(fmaxf(rintf(expf(-da / cc2) * 255.0f), 0.0f), 255.0f);
        float q3 = fminf(fmaxf(rintf(expf(-db / cc0) * 255.0f), 0.0f), 255.0f);
        float q4 = fminf(fmaxf(rintf(expf(-db / cc1) * 255.0f), 0.0f), 255.0f);
        float q5 = fminf(fmaxf(rintf(expf(-db / cc2) * 255.0f), 0.0f), 255.0f);

        float2* o = (float2*)(out + ((size_t)((b * H + i) * W) + w0 + tx) * 6);
        o[0] = make_float2(q0, q1);
        o[1] = make_float2(q2, q3);
        o[2] = make_float2(q4, q5);
    }
}

extern "C" void kernel_launch(void* const* d_in, const int* in_sizes, int n_in,
                              void* d_out, int out_size, void* d_ws, size_t ws_size,
                              hipStream_t stream) {
    const int* tri   = (const int*)d_in[0];
    float* out       = (float*)d_out;
    uint32_t* packed = (uint32_t*)d_ws;   // B*H*W*4 = 1.6 MB scratch

    hipLaunchKernelGGL(row_edt_kernel, dim3(B * H), dim3(W), 0, stream, tri, packed);
    hipLaunchKernelGGL(col_edt_kernel, dim3(W / WTILE, H / ITILE, B), dim3(256), 0, stream,
                       packed, out);
}

// Round 2
// 80.471 us; speedup vs baseline: 1.4901x; 1.4901x over previous
//
#include <hip/hip_runtime.h>
#include <cstdint>
#include <math.h>

// Problem constants (fixed by the reference: trimap [4,320,320,1] int32).
constexpr int B = 4, H = 320, W = 320;

typedef float v2f __attribute__((ext_vector_type(2)));
typedef float v4f __attribute__((ext_vector_type(4)));

// ---------------------------------------------------------------------------
// Nearest-set-bit distance in a 320-bit mask (5 x u64), position w.
// Distances are <=319 when a bit exists; 1000 sentinel otherwise (matches the
// reference's BIG sentinel after quantization: exp(-1e6/2s^2) -> 0).
// ---------------------------------------------------------------------------
__device__ __forceinline__ int nearest_dist(const uint64_t* m, int w) {
    const int wd = w >> 6, bit = w & 63;
    int dl = 1000;
    const uint64_t x = m[wd] << (63 - bit);     // bits [0..bit], 'bit' at MSB
    if (x) {
        dl = __builtin_clzll(x);
    } else {
        int d = bit + 1;
        #pragma unroll
        for (int k = 1; k < 5; ++k) {
            const int idx = wd - k;
            if (idx >= 0) {
                const uint64_t mw = m[idx];
                if (mw) { dl = d + __builtin_clzll(mw); break; }
            }
            d += 64;
        }
    }
    int dr = 1000;
    const uint64_t y = m[wd] >> bit;            // bits [bit..], 'bit' at LSB
    if (y) {
        dr = __builtin_ctzll(y);
    } else {
        int d = 64 - bit;
        #pragma unroll
        for (int k = 1; k < 5; ++k) {
            const int idx = wd + k;
            if (idx < 5) {
                const uint64_t mw = m[idx];
                if (mw) { dr = d + __builtin_ctzll(mw); break; }
            }
            d += 64;
        }
    }
    return min(dl, dr);
}

// ---------------------------------------------------------------------------
// Kernel 1: exact 1-D row EDT for values 0 and 255 via ballot bitmasks.
// One block per row (320 threads = 5 waves). Output g = d^2 as float2
// (ch0 = value0, ch1 = value255), stored interleaved by row parity so that
// kernel 2 can read [g(2kk), g(2kk+1)] for one column as a single float4:
//   f4 cell index = (b*160 + (h>>1))*W + w ; parity h&1 selects the float2.
// ---------------------------------------------------------------------------
__global__ __launch_bounds__(320) void row_edt_kernel(const int* __restrict__ tri,
                                                      float2* __restrict__ g2) {
    __shared__ uint64_t sm[2][5];
    const int h = blockIdx.x, b = blockIdx.y;
    const int w = threadIdx.x;
    const int lane = w & 63, wv = w >> 6;
    const int v = tri[(b * H + h) * W + w];
    const uint64_t b0 = __ballot(v == 0);
    const uint64_t b1 = __ballot(v == 255);
    if (lane == 0) { sm[0][wv] = b0; sm[1][wv] = b1; }
    __syncthreads();
    uint64_t m0[5], m1[5];
    #pragma unroll
    for (int k = 0; k < 5; ++k) { m0[k] = sm[0][k]; m1[k] = sm[1][k]; }
    const float d0 = (float)nearest_dist(m0, w);
    const float d1 = (float)nearest_dist(m1, w);
    g2[((((size_t)b * 160 + (h >> 1)) * W + w) << 1) + (h & 1)] =
        make_float2(d0 * d0, d1 * d1);
}

// ---------------------------------------------------------------------------
// Kernel 2: column min-plus  D2[i,w] = min_k g[k,w] + (i-k)^2  (exact in f32:
// every term is an integer < 2^24), fused Gaussian/quantize epilogue.
// Block: 32 w x 32 i (256 threads, 8 i-groups x 32 w, 4 i per thread).
// Inner loop processes 2 k per iteration with packed-f32 math:
//   even k:  t0 = dy*dy + g_even              (v_pk_fma_f32, both channels)
//   odd  k:  (dy-1)^2 + g_odd = dy*(dy-2) + (g_odd+1) = pk_fma(dy, dyN, g1p)
// where dyN = dy-2 is also the next iteration's dy. Mins via v_min3_f32.
// LDS staged in two 40KB phases (80 kk-rows each) to stay under 64KB/block.
// ---------------------------------------------------------------------------
__global__ __launch_bounds__(256) void col_edt_kernel(const v4f* __restrict__ g4,
                                                      float* __restrict__ out) {
    __shared__ v4f lds[80 * 32];                 // 40 KB
    const int w0 = blockIdx.x * 32;
    const int i0 = blockIdx.y * 32;
    const int b  = blockIdx.z;
    const int tid = threadIdx.x;
    const int tx = tid & 31, tg = tid >> 5;

    float mnx[4], mny[4];
    v2f dyE[4];
    const v2f cm2 = {-2.f, -2.f};
    const v2f cp1 = {1.f, 1.f};
    #pragma unroll
    for (int r = 0; r < 4; ++r) {
        mnx[r] = 1e30f;
        mny[r] = 1e30f;
        const float iv = (float)(i0 + tg + 8 * r);
        dyE[r] = (v2f){iv, iv};
    }

    const v4f* src = g4 + (size_t)b * 160 * W;
    for (int p = 0; p < 2; ++p) {
        #pragma unroll
        for (int s = 0; s < 10; ++s) {
            const int idx = tid + s * 256;
            lds[idx] = src[(p * 80 + (idx >> 5)) * W + w0 + (idx & 31)];
        }
        __syncthreads();

        #pragma unroll 4
        for (int kk = 0; kk < 80; ++kk) {
            const v4f g = lds[kk * 32 + tx];
            const v2f gk = g.xy;                 // {g0, g1} at k = even
            const v2f go = g.zw;                 // {g0, g1} at k = odd
            v2f g1p;
            asm("v_pk_add_f32 %0, %1, %2" : "=v"(g1p) : "v"(go), "v"(cp1));
            #pragma unroll
            for (int r = 0; r < 4; ++r) {
                v2f t0, dyN, t1;
                asm("v_pk_fma_f32 %0, %1, %1, %2" : "=v"(t0) : "v"(dyE[r]), "v"(gk));
                asm("v_pk_add_f32 %0, %1, %2" : "=v"(dyN) : "v"(dyE[r]), "v"(cm2));
                asm("v_pk_fma_f32 %0, %1, %2, %3" : "=v"(t1) : "v"(dyE[r]), "v"(dyN), "v"(g1p));
                float nx, ny;
                asm("v_min3_f32 %0, %1, %2, %3" : "=v"(nx) : "v"(mnx[r]), "v"(t0.x), "v"(t1.x));
                asm("v_min3_f32 %0, %1, %2, %3" : "=v"(ny) : "v"(mny[r]), "v"(t0.y), "v"(t1.y));
                mnx[r] = nx;
                mny[r] = ny;
                dyE[r] = dyN;
            }
        }
        __syncthreads();
    }

    // Epilogue: 2*sigma^2 for sigma = 6.4, 25.6, 51.2. True division + rintf
    // (half-even) mirrors jnp's clip(round(exp(-d2/(2 s^2)) * 255), 0, 255);
    // validated absmax == 0.0 in round 1 with this exact formula.
    const float cc0 = 81.92f, cc1 = 1310.72f, cc2 = 5242.88f;
    #pragma unroll
    for (int r = 0; r < 4; ++r) {
        const int i = i0 + tg + 8 * r;
        const float da = mnx[r];
        const float db = mny[r];
        const float q0 = fminf(fmaxf(rintf(expf(-da / cc0) * 255.0f), 0.0f), 255.0f);
        const float q1 = fminf(fmaxf(rintf(expf(-da / cc1) * 255.0f), 0.0f), 255.0f);
        const float q2 = fminf(fmaxf(rintf(expf(-da / cc2) * 255.0f), 0.0f), 255.0f);
        const float q3 = fminf(fmaxf(rintf(expf(-db / cc0) * 255.0f), 0.0f), 255.0f);
        const float q4 = fminf(fmaxf(rintf(expf(-db / cc1) * 255.0f), 0.0f), 255.0f);
        const float q5 = fminf(fmaxf(rintf(expf(-db / cc2) * 255.0f), 0.0f), 255.0f);

        float2* o = (float2*)(out + ((size_t)((b * H + i) * W) + w0 + tx) * 6);
        o[0] = make_float2(q0, q1);
        o[1] = make_float2(q2, q3);
        o[2] = make_float2(q4, q5);
    }
}

extern "C" void kernel_launch(void* const* d_in, const int* in_sizes, int n_in,
                              void* d_out, int out_size, void* d_ws, size_t ws_size,
                              hipStream_t stream) {
    const int* tri = (const int*)d_in[0];
    float* out     = (float*)d_out;
    float2* g2     = (float2*)d_ws;      // B*160*W float4 cells = 3.3 MB scratch

    hipLaunchKernelGGL(row_edt_kernel, dim3(H, B), dim3(320), 0, stream, tri, g2);
    hipLaunchKernelGGL(col_edt_kernel, dim3(W / 32, H / 32, B), dim3(256), 0, stream,
                       (const v4f*)d_ws, out);
}

// Round 3
// 62.995 us; speedup vs baseline: 1.9035x; 1.2774x over previous
//
#include <hip/hip_runtime.h>
#include <cstdint>
#include <math.h>

// Problem constants (fixed by the reference: trimap [4,320,320,1] int32).
constexpr int B = 4, H = 320, W = 320;

// ---------------------------------------------------------------------------
// Nearest-set-bit distance in a 320-bit mask (5 x u64), position w.
// <=319 when a bit exists; 1000 sentinel otherwise (exp() of it quantizes to
// 0, matching the reference's BIG sentinel — validated absmax==0 twice).
// ---------------------------------------------------------------------------
__device__ __forceinline__ int nearest_dist(const uint64_t* m, int w) {
    const int wd = w >> 6, bit = w & 63;
    int dl = 1000;
    const uint64_t x = m[wd] << (63 - bit);     // bits [0..bit], 'bit' at MSB
    if (x) {
        dl = __builtin_clzll(x);
    } else {
        int d = bit + 1;
        #pragma unroll
        for (int k = 1; k < 5; ++k) {
            const int idx = wd - k;
            if (idx >= 0) {
                const uint64_t mw = m[idx];
                if (mw) { dl = d + __builtin_clzll(mw); break; }
            }
            d += 64;
        }
    }
    int dr = 1000;
    const uint64_t y = m[wd] >> bit;            // bits [bit..], 'bit' at LSB
    if (y) {
        dr = __builtin_ctzll(y);
    } else {
        int d = 64 - bit;
        #pragma unroll
        for (int k = 1; k < 5; ++k) {
            const int idx = wd + k;
            if (idx < 5) {
                const uint64_t mw = m[idx];
                if (mw) { dr = d + __builtin_ctzll(mw); break; }
            }
            d += 64;
        }
    }
    return min(dl, dr);
}

// ---------------------------------------------------------------------------
// Kernel 1: exact 1-D row EDT for values 0 and 255 via ballot bitmasks.
// One block per (b,h) row, 320 threads (5 waves). Plain float2 output:
// g[b][h][w] = { d0^2, d1^2 }.
// ---------------------------------------------------------------------------
__global__ __launch_bounds__(320) void row_edt_kernel(const int* __restrict__ tri,
                                                      float2* __restrict__ g) {
    __shared__ uint64_t sm[2][5];
    const int h = blockIdx.x, b = blockIdx.y;
    const int w = threadIdx.x;
    const int lane = w & 63, wv = w >> 6;
    const int v = tri[(b * H + h) * W + w];
    const uint64_t b0 = __ballot(v == 0);
    const uint64_t b1 = __ballot(v == 255);
    if (lane == 0) { sm[0][wv] = b0; sm[1][wv] = b1; }
    __syncthreads();
    uint64_t m0[5], m1[5];
    #pragma unroll
    for (int k = 0; k < 5; ++k) { m0[k] = sm[0][k]; m1[k] = sm[1][k]; }
    const float d0 = (float)nearest_dist(m0, w);
    const float d1 = (float)nearest_dist(m1, w);
    g[(size_t)(b * H + h) * W + w] = make_float2(d0 * d0, d1 * d1);
}

// ---------------------------------------------------------------------------
// Kernel 2: column min-plus  D2[i,w] = min_k g[k,w] + (i-k)^2  via outward
// two-pointer scan with wave-uniform early exit. All terms are integers
// < 2^24 -> exact in f32. Exit: after step s all uncovered k have
// (i-k)^2 >= (s+1)^2, so if (s+1)^2 >= max(min0,min1) for every lane, done.
// Edge clamp is harmless: the clamped candidate g[edge]+s^2 dominates the
// already-seen g[edge]+(i-edge)^2. Cap s at 319 = full coverage for any
// input. For the fixed random trimap (match density 1/3 per value) the scan
// exits after ~4-6 steps.
// Block: 256 threads = 4 waves; wave = 64 consecutive w (coalesced 512B
// loads, one i per thread). Grid (W/64, H/4, B) = 1600 blocks. No LDS.
// ---------------------------------------------------------------------------
__global__ __launch_bounds__(256) void col_scan_kernel(const float2* __restrict__ g,
                                                       float* __restrict__ out) {
    const int tid = threadIdx.x;
    const int tx = tid & 63, tg = tid >> 6;
    const int w  = blockIdx.x * 64 + tx;
    const int i  = blockIdx.y * 4 + tg;
    const int b  = blockIdx.z;

    const char* gp = (const char*)(g + (size_t)b * H * W);
    const int rowB = W * 8;                       // bytes per k-row
    const int off0 = (i * W + w) * 8;
    const int lo   = w * 8;                       // k = 0
    const int hi   = (319 * W + w) * 8;           // k = 319

    const float2 g0 = *(const float2*)(gp + off0);
    float mnx = g0.x, mny = g0.y;                 // s = 0 candidate
    int offL = off0, offR = off0;
    float sf = 1.0f;

    for (int s = 1; s <= 319; ++s) {
        offL = max(offL - rowB, lo);
        offR = min(offR + rowB, hi);
        const float2 gL = *(const float2*)(gp + offL);
        const float2 gR = *(const float2*)(gp + offR);
        const float dd = sf * sf;
        mnx = fminf(mnx, fminf(dd + gL.x, dd + gR.x));   // -> v_min3_f32
        mny = fminf(mny, fminf(dd + gL.y, dd + gR.y));
        sf += 1.0f;
        const float ddn = sf * sf;                // (s+1)^2
        if (__all(ddn >= fmaxf(mnx, mny))) break;
    }

    // Epilogue: 2*sigma^2 for sigma = 6.4, 25.6, 51.2. True division + rintf
    // (half-even) mirrors jnp's clip(round(exp(-d2/(2 s^2))*255), 0, 255);
    // validated absmax == 0.0 in rounds 1 and 2.
    const float cc0 = 81.92f, cc1 = 1310.72f, cc2 = 5242.88f;
    const float q0 = fminf(fmaxf(rintf(expf(-mnx / cc0) * 255.0f), 0.0f), 255.0f);
    const float q1 = fminf(fmaxf(rintf(expf(-mnx / cc1) * 255.0f), 0.0f), 255.0f);
    const float q2 = fminf(fmaxf(rintf(expf(-mnx / cc2) * 255.0f), 0.0f), 255.0f);
    const float q3 = fminf(fmaxf(rintf(expf(-mny / cc0) * 255.0f), 0.0f), 255.0f);
    const float q4 = fminf(fmaxf(rintf(expf(-mny / cc1) * 255.0f), 0.0f), 255.0f);
    const float q5 = fminf(fmaxf(rintf(expf(-mny / cc2) * 255.0f), 0.0f), 255.0f);

    float2* o = (float2*)(out + ((size_t)((b * H + i) * W) + w) * 6);
    o[0] = make_float2(q0, q1);
    o[1] = make_float2(q2, q3);
    o[2] = make_float2(q4, q5);
}

extern "C" void kernel_launch(void* const* d_in, const int* in_sizes, int n_in,
                              void* d_out, int out_size, void* d_ws, size_t ws_size,
                              hipStream_t stream) {
    const int* tri = (const int*)d_in[0];
    float* out     = (float*)d_out;
    float2* g      = (float2*)d_ws;   // B*H*W float2 = 3.3 MB scratch

    hipLaunchKernelGGL(row_edt_kernel, dim3(H, B), dim3(320), 0, stream, tri, g);
    hipLaunchKernelGGL(col_scan_kernel, dim3(W / 64, H / 4, B), dim3(256), 0, stream,
                       g, out);
}